// Round 4
// baseline (70.523 us; speedup 1.0000x reference)
//
#include <hip/hip_runtime.h>

#define BATCH 4096
#define TLEN  750
#define NK    6            // pair offsets k = 1..6 (k=0 contributes exactly 0)
#define CPT   4            // columns per thread
#define NTH1  192          // K1 block size (3 waves); threads 0..187 own columns
#define NCG   188          // ceil(750/4)
#define GGRP  512          // row groups (RPG = 8 rows each)
#define RPG   (BATCH/GGRP)
#define PSTR  752          // i-stride inside partials (16B-aligned)
#define HALF  (NK*PSTR)    // 4512 floats: s1 slots (s2 at +HALF)
#define PSZ   (2*HALF)     // 9024 floats per group
#define NCH   4            // chunks over groups in K2
#define GPC   (GGRP/NCH)   // 128 groups per chunk
#define NSB   36           // slot-blocks per chunk: 36*256 >= 9024
#define K2GRID (NCH*NSB)   // 144 blocks

// ---------------- helpers ----------------

template<int NW>
__device__ __forceinline__ float block_reduce(float v, float* red) {
    #pragma unroll
    for (int off = 32; off > 0; off >>= 1) v += __shfl_down(v, off, 64);
    const int t = threadIdx.x;
    if ((t & 63) == 0) red[t >> 6] = v;
    __syncthreads();
    float r = 0.f;
    if (t == 0) {
        #pragma unroll
        for (int w = 0; w < NW; ++w) r += red[w];
    }
    __syncthreads();
    return r;
}

// Load the 10-float window [i0 .. i0+9] as 5 aligned float2 (i0 even, pitch even
// -> always 8B aligned). nld clamps trailing loads for the last threads; unloaded
// entries keep previous (finite) values and feed only provably-unread slots.
__device__ __forceinline__ void load_win(const float* __restrict__ row, int i0,
                                         int nld, float* w) {
    #pragma unroll
    for (int u = 0; u < 5; ++u) {
        if (u < nld) {
            const float2 v = *reinterpret_cast<const float2*>(row + i0 + 2 * u);
            w[2 * u] = v.x; w[2 * u + 1] = v.y;
        }
    }
}

__device__ __forceinline__ void compute_row(const float* wa, const float* wb,
                                            int i0, float s1[CPT][NK],
                                            float s2[CPT][NK], float& res) {
    #pragma unroll
    for (int c = 0; c < CPT; ++c) {
        const float av = wa[c], bv = wb[c];
        #pragma unroll
        for (int k = 1; k <= NK; ++k) {
            const float d = av - wa[c + k];
            s1[c][k - 1] = fmaf(d, d, s1[c][k - 1]);
            s2[c][k - 1] += fabsf(bv - wb[c + k]);
        }
        if (i0 + c < TLEN) { const float rr = av - bv; res = fmaf(rr, rr, res); }
    }
}

// ---------------- K1: per-group pair partials ----------------
__global__ __launch_bounds__(NTH1) void actloss_k1(
        const float* __restrict__ a, const float* __restrict__ a2,
        float* __restrict__ p, float* __restrict__ resp,
        unsigned* __restrict__ ctr) {
    const int t  = threadIdx.x;
    const int g  = blockIdx.x;
    const int i0 = t * CPT;
    const int b0 = g * RPG;
    if (g == 0 && t == 0) *ctr = 0u;   // visible to K2 via kernel boundary

    const int nld = (t < NCG) ? min(5, (TLEN - 1 - i0) / 2 + 1) : 0;

    float s1[CPT][NK], s2[CPT][NK];
    #pragma unroll
    for (int c = 0; c < CPT; ++c)
        #pragma unroll
        for (int k = 0; k < NK; ++k) { s1[c][k] = 0.f; s2[c][k] = 0.f; }
    float res = 0.f;

    float wa[10] = {}, wb[10] = {}, na[10] = {}, nb[10] = {};

    load_win(a  + (size_t)b0 * TLEN, i0, nld, wa);
    load_win(a2 + (size_t)b0 * TLEN, i0, nld, wb);
    #pragma unroll
    for (int rp = 0; rp < RPG / 2; ++rp) {
        const int r0 = b0 + 2 * rp;
        load_win(a  + (size_t)(r0 + 1) * TLEN, i0, nld, na);
        load_win(a2 + (size_t)(r0 + 1) * TLEN, i0, nld, nb);
        compute_row(wa, wb, i0, s1, s2, res);
        if (rp < RPG / 2 - 1) {
            load_win(a  + (size_t)(r0 + 2) * TLEN, i0, nld, wa);
            load_win(a2 + (size_t)(r0 + 2) * TLEN, i0, nld, wb);
        }
        compute_row(na, nb, i0, s1, s2, res);
    }

    if (t < NCG) {
        float* pg = p + (size_t)g * PSZ;
        #pragma unroll
        for (int k = 0; k < NK; ++k) {
            *reinterpret_cast<float4*>(pg + (size_t)k * PSTR + i0) =
                make_float4(s1[0][k], s1[1][k], s1[2][k], s1[3][k]);
            *reinterpret_cast<float4*>(pg + HALF + (size_t)k * PSTR + i0) =
                make_float4(s2[0][k], s2[1][k], s2[2][k], s2[3][k]);
        }
    }

    __shared__ float red[3];
    const float rsum = block_reduce<3>(res, red);
    if (t == 0) resp[g] = rsum;
}

// ---------------- K2: chunk-reduce + last-block finish ----------------
__global__ __launch_bounds__(256) void actloss_k2(
        const float* __restrict__ p, const float* __restrict__ resp,
        float* __restrict__ out2, unsigned* __restrict__ ctr,
        float* __restrict__ out) {
    const int t  = threadIdx.x;
    const int ch = blockIdx.x / NSB;
    const int sb = blockIdx.x % NSB;
    const int slot = sb * 256 + t;

    if (slot < PSZ) {
        const float* base = p + (size_t)ch * GPC * PSZ + slot;
        float s = 0.f;
        #pragma unroll 8
        for (int q = 0; q < GPC; ++q) s += base[(size_t)q * PSZ];
        out2[(size_t)ch * PSZ + slot] = s;
    }

    // completion counter: last block finishes the job
    __threadfence();
    __syncthreads();
    __shared__ unsigned last;
    if (t == 0) last = (atomicAdd(ctr, 1u) == (unsigned)(K2GRID - 1)) ? 1u : 0u;
    __syncthreads();
    if (!last) return;
    __threadfence();   // acquire: see all blocks' out2 stores

    __shared__ float Tl[HALF];   // 18 KB
    for (int m = t; m < HALF; m += 256) {
        float v1 = 0.f, v2 = 0.f;
        #pragma unroll
        for (int c = 0; c < NCH; ++c) {
            v1 += out2[(size_t)c * PSZ + m];
            v2 += out2[(size_t)c * PSZ + HALF + m];
        }
        Tl[m] = expf(-0.5f * v1) * v2;
    }
    __syncthreads();

    float acc = 0.f;
    for (int idx = t; idx < TLEN * 11; idx += 256) {
        const int i = idx / 11, j = idx - i * 11;
        int c = i + j - 6;
        c = c < 0 ? 0 : (c > TLEN - 1 ? TLEN - 1 : c);
        const int k = i < c ? c - i : i - c;
        if (k > 0) {
            const int lo = i < c ? i : c;
            acc += Tl[(k - 1) * PSTR + lo];
        }
    }
    float racc = 0.f;
    for (int q = t; q < GGRP; q += 256) racc += resp[q];

    __shared__ float red[4];
    const float accR  = block_reduce<4>(acc, red);
    const float raccR = block_reduce<4>(racc, red);
    if (t == 0) out[0] = (accR + 0.1f * raccR) * (1.0f / (float)BATCH);
}

// ---------------- fallback slow path (round-1, known-good) ----------------

__global__ __launch_bounds__(256) void actloss_col_kernel(
        const float* __restrict__ a, const float* __restrict__ a2,
        float* __restrict__ part) {
    const int i = blockIdx.x;
    const int t = threadIdx.x;
    __shared__ float red[4];
    int cidx[11];
    #pragma unroll
    for (int j = 0; j < 11; ++j) {
        int c = i + j - 6;
        cidx[j] = c < 0 ? 0 : (c > TLEN - 1 ? TLEN - 1 : c);
    }
    float s1[11], s2[11];
    #pragma unroll
    for (int j = 0; j < 11; ++j) { s1[j] = 0.f; s2[j] = 0.f; }
    float resacc = 0.f;
    for (int b = t; b < BATCH; b += 256) {
        const float* arow  = a  + (size_t)b * TLEN;
        const float* a2row = a2 + (size_t)b * TLEN;
        const float ai = arow[i], a2i = a2row[i];
        const float r = ai - a2i;
        resacc = fmaf(r, r, resacc);
        #pragma unroll
        for (int j = 0; j < 11; ++j) {
            const float d = ai - arow[cidx[j]];
            s1[j] = fmaf(d, d, s1[j]);
            s2[j] += fabsf(a2i - a2row[cidx[j]]);
        }
    }
    float term = 0.f;
    #pragma unroll
    for (int j = 0; j < 11; ++j) {
        const float s1r = block_reduce<4>(s1[j], red);
        const float s2r = block_reduce<4>(s2[j], red);
        if (t == 0) term += expf(-0.5f * s1r) * s2r;
    }
    const float resr = block_reduce<4>(resacc, red);
    if (t == 0) part[i] = (term + 0.1f * resr) * (1.0f / (float)BATCH);
}

__global__ __launch_bounds__(256) void actloss_fallback_reduce(
        const float* __restrict__ part, float* __restrict__ out) {
    __shared__ float red[4];
    float v = 0.f;
    for (int k = threadIdx.x; k < TLEN; k += 256) v += part[k];
    const float r = block_reduce<4>(v, red);
    if (threadIdx.x == 0) out[0] = r;
}

// ---------------- launcher ----------------

extern "C" void kernel_launch(void* const* d_in, const int* in_sizes, int n_in,
                              void* d_out, int out_size, void* d_ws, size_t ws_size,
                              hipStream_t stream) {
    const float* a  = (const float*)d_in[0];   // actioness
    const float* a2 = (const float*)d_in[1];   // actioness_2
    float* out = (float*)d_out;
    float* ws  = (float*)d_ws;

    const size_t need = ((size_t)GGRP * PSZ + (size_t)NCH * PSZ + GGRP + 16)
                        * sizeof(float);
    if (ws_size >= need) {
        float*    p    = ws;
        float*    out2 = p + (size_t)GGRP * PSZ;
        float*    resp = out2 + (size_t)NCH * PSZ;
        unsigned* ctr  = (unsigned*)(resp + GGRP);
        actloss_k1<<<GGRP,   NTH1, 0, stream>>>(a, a2, p, resp, ctr);
        actloss_k2<<<K2GRID, 256,  0, stream>>>(p, resp, out2, ctr, out);
    } else {
        float* part = ws;   // 750 floats
        actloss_col_kernel<<<TLEN, 256, 0, stream>>>(a, a2, part);
        actloss_fallback_reduce<<<1, 256, 0, stream>>>(part, out);
    }
}

// Round 5
// 55.033 us; speedup vs baseline: 1.2815x; 1.2815x over previous
//
#include <hip/hip_runtime.h>

#define BATCH  4096
#define TLEN   750
#define NK     6               // pair offsets k=1..6 (k=0 contributes exactly 0)
#define OWN    58              // owned columns per 64-lane wave (6 halo lanes)
#define NSTRIP 13              // 13*58 = 754 >= 750
#define WPB    4               // waves per block
#define NTH    256
#define RPB    32              // rows per block
#define RPW    (RPB/WPB)       // 8 rows per wave
#define NG     (BATCH/RPB)     // 128 row-groups
#define QSZ    (2*NK*64)       // 768 floats per (strip,group): 12 quantities x 64 lanes
#define SLOTS  (NSTRIP*QSZ)    // 9984 (= 39*256 exactly)
#define NCH    8               // chunks over row-groups in K2
#define GPC    (NG/NCH)        // 16 groups per chunk
#define K2RED  (SLOTS/256)     // 39 reduce-blocks per chunk
#define K2GRID (NCH*K2RED)     // 312
#define TP     752             // pitch of T rows (i-index)

// ---------------- helpers ----------------

template<int NW>
__device__ __forceinline__ float block_reduce(float v, float* red) {
    #pragma unroll
    for (int off = 32; off > 0; off >>= 1) v += __shfl_down(v, off, 64);
    const int t = threadIdx.x;
    if ((t & 63) == 0) red[t >> 6] = v;
    __syncthreads();
    float r = 0.f;
    if (t == 0) {
        #pragma unroll
        for (int w = 0; w < NW; ++w) r += red[w];
    }
    __syncthreads();
    return r;
}

// ---------------- K1: strip x row-group pair partials ----------------
// Lane = one column. Window neighbors come from __shfl_down (k=1..6).
// Lanes 58..63 are halo (their shuffles cross the wave edge -> garbage, but
// finite); their slots are never consumed downstream. Strip 12 clamps col to
// 749; columns >= 750 are masked out of res and skipped by the finish map.
__global__ __launch_bounds__(NTH) void actloss_k1(
        const float* __restrict__ a, const float* __restrict__ a2,
        float* __restrict__ p, float* __restrict__ resp,
        unsigned* __restrict__ ctr) {
    const int t = threadIdx.x;
    const int w = t >> 6;
    const int l = t & 63;
    const int s = (int)(blockIdx.x % NSTRIP);
    const int g = (int)(blockIdx.x / NSTRIP);
    if (blockIdx.x == 0 && t == 0) *ctr = 0u;   // K2 sees this via stream order

    const int colr = s * OWN + l;
    const int col  = colr < TLEN - 1 ? colr : TLEN - 1;
    const bool own = (l < OWN) && (colr < TLEN);

    float s1[NK], s2[NK];
    #pragma unroll
    for (int k = 0; k < NK; ++k) { s1[k] = 0.f; s2[k] = 0.f; }
    float res = 0.f;

    const int b0 = g * RPB + w * RPW;
    #pragma unroll
    for (int r = 0; r < RPW; ++r) {
        const size_t off = (size_t)(b0 + r) * TLEN + col;
        const float av = a[off];
        const float bv = a2[off];
        #pragma unroll
        for (int k = 1; k <= NK; ++k) {
            const float ak = __shfl_down(av, k, 64);
            const float bk = __shfl_down(bv, k, 64);
            const float d = av - ak;
            s1[k - 1] = fmaf(d, d, s1[k - 1]);
            s2[k - 1] += fabsf(bv - bk);
        }
        if (own) { const float rr = av - bv; res = fmaf(rr, rr, res); }
    }

    // cross-wave reduce in LDS -> one 768-float partial per block
    __shared__ float lds[WPB][QSZ];
    __shared__ float rw[WPB];
    #pragma unroll
    for (int k = 0; k < NK; ++k) {
        lds[w][k * 64 + l]        = s1[k];
        lds[w][(NK + k) * 64 + l] = s2[k];
    }
    #pragma unroll
    for (int off = 32; off > 0; off >>= 1) res += __shfl_down(res, off, 64);
    if (l == 0) rw[w] = res;
    __syncthreads();

    float* pg = p + ((size_t)g * NSTRIP + s) * QSZ;
    for (int q = t; q < QSZ; q += NTH)
        pg[q] = (lds[0][q] + lds[1][q]) + (lds[2][q] + lds[3][q]);
    if (t == 0) resp[blockIdx.x] = (rw[0] + rw[1]) + (rw[2] + rw[3]);
}

// ---------------- K2: chunk-reduce + last-block finish ----------------
__global__ __launch_bounds__(256) void actloss_k2(
        const float* __restrict__ p, const float* __restrict__ resp,
        float* __restrict__ out3, unsigned* __restrict__ ctr,
        float* __restrict__ out) {
    const int t  = threadIdx.x;
    const int ch = (int)(blockIdx.x / K2RED);
    const int sb = (int)(blockIdx.x % K2RED);
    const int slot = sb * 256 + t;   // SLOTS = 39*256: always in range

    {
        const float* base = p + (size_t)ch * GPC * SLOTS + slot;
        float sum = 0.f;
        #pragma unroll
        for (int q = 0; q < GPC; ++q) sum += base[(size_t)q * SLOTS];
        out3[(size_t)ch * SLOTS + slot] = sum;
    }

    __threadfence();
    __syncthreads();
    __shared__ unsigned last;
    if (t == 0) last = (atomicAdd(ctr, 1u) == (unsigned)(K2GRID - 1)) ? 1u : 0u;
    __syncthreads();
    if (!last) return;
    __threadfence();   // acquire: see all blocks' out3 stores

    __shared__ float sm[SLOTS];      // ~39 KB
    __shared__ float Tl[NK * TP];    // ~18 KB
    for (int q = t; q < SLOTS; q += 256) {
        float v = 0.f;
        #pragma unroll
        for (int c = 0; c < NCH; ++c) v += out3[(size_t)c * SLOTS + q];
        sm[q] = v;
    }
    __syncthreads();

    // T[k][i] = exp(-0.5*S1) * S2 for valid pairs (i, i+k), i+k <= 749
    for (int e = t; e < NSTRIP * OWN * NK; e += 256) {
        const int s   = e / (OWN * NK);
        const int rem = e % (OWN * NK);
        const int l   = rem / NK;
        const int k   = rem % NK + 1;
        const int i   = s * OWN + l;
        if (i + k <= TLEN - 1) {
            const int sl = s * QSZ + (k - 1) * 64 + l;
            Tl[(k - 1) * TP + i] = expf(-0.5f * sm[sl]) * sm[sl + NK * 64];
        }
    }
    __syncthreads();

    // map the 8250 (i,j) window terms onto pairs
    float acc = 0.f;
    for (int idx = t; idx < TLEN * 11; idx += 256) {
        const int i = idx / 11, j = idx - i * 11;
        int c = i + j - 6;
        c = c < 0 ? 0 : (c > TLEN - 1 ? TLEN - 1 : c);
        const int k = i < c ? c - i : i - c;
        if (k > 0) acc += Tl[(k - 1) * TP + (i < c ? i : c)];
    }
    float racc = 0.f;
    for (int q = t; q < NG * NSTRIP; q += 256) racc += resp[q];

    __shared__ float red[4];
    const float accR  = block_reduce<4>(acc, red);
    const float raccR = block_reduce<4>(racc, red);
    if (t == 0) out[0] = (accR + 0.1f * raccR) * (1.0f / (float)BATCH);
}

// ---------------- fallback slow path (round-1, known-good) ----------------

__global__ __launch_bounds__(256) void actloss_col_kernel(
        const float* __restrict__ a, const float* __restrict__ a2,
        float* __restrict__ part) {
    const int i = blockIdx.x;
    const int t = threadIdx.x;
    __shared__ float red[4];
    int cidx[11];
    #pragma unroll
    for (int j = 0; j < 11; ++j) {
        int c = i + j - 6;
        cidx[j] = c < 0 ? 0 : (c > TLEN - 1 ? TLEN - 1 : c);
    }
    float s1[11], s2[11];
    #pragma unroll
    for (int j = 0; j < 11; ++j) { s1[j] = 0.f; s2[j] = 0.f; }
    float resacc = 0.f;
    for (int b = t; b < BATCH; b += 256) {
        const float* arow  = a  + (size_t)b * TLEN;
        const float* a2row = a2 + (size_t)b * TLEN;
        const float ai = arow[i], a2i = a2row[i];
        const float r = ai - a2i;
        resacc = fmaf(r, r, resacc);
        #pragma unroll
        for (int j = 0; j < 11; ++j) {
            const float d = ai - arow[cidx[j]];
            s1[j] = fmaf(d, d, s1[j]);
            s2[j] += fabsf(a2i - a2row[cidx[j]]);
        }
    }
    float term = 0.f;
    #pragma unroll
    for (int j = 0; j < 11; ++j) {
        const float s1r = block_reduce<4>(s1[j], red);
        const float s2r = block_reduce<4>(s2[j], red);
        if (t == 0) term += expf(-0.5f * s1r) * s2r;
    }
    const float resr = block_reduce<4>(resacc, red);
    if (t == 0) part[i] = (term + 0.1f * resr) * (1.0f / (float)BATCH);
}

__global__ __launch_bounds__(256) void actloss_fallback_reduce(
        const float* __restrict__ part, float* __restrict__ out) {
    __shared__ float red[4];
    float v = 0.f;
    for (int k = threadIdx.x; k < TLEN; k += 256) v += part[k];
    const float r = block_reduce<4>(v, red);
    if (threadIdx.x == 0) out[0] = r;
}

// ---------------- launcher ----------------

extern "C" void kernel_launch(void* const* d_in, const int* in_sizes, int n_in,
                              void* d_out, int out_size, void* d_ws, size_t ws_size,
                              hipStream_t stream) {
    const float* a  = (const float*)d_in[0];   // actioness
    const float* a2 = (const float*)d_in[1];   // actioness_2
    float* out = (float*)d_out;
    float* ws  = (float*)d_ws;

    const size_t need = ((size_t)NG * SLOTS + (size_t)NCH * SLOTS
                         + (size_t)NG * NSTRIP + 16) * sizeof(float);
    if (ws_size >= need) {
        float*    p    = ws;
        float*    out3 = p + (size_t)NG * SLOTS;
        float*    resp = out3 + (size_t)NCH * SLOTS;
        unsigned* ctr  = (unsigned*)(resp + (size_t)NG * NSTRIP);
        actloss_k1<<<NG * NSTRIP, NTH, 0, stream>>>(a, a2, p, resp, ctr);
        actloss_k2<<<K2GRID, 256, 0, stream>>>(p, resp, out3, ctr, out);
    } else {
        float* part = ws;   // 750 floats
        actloss_col_kernel<<<TLEN, 256, 0, stream>>>(a, a2, part);
        actloss_fallback_reduce<<<1, 256, 0, stream>>>(part, out);
    }
}

// Round 6
// 36.155 us; speedup vs baseline: 1.9506x; 1.5221x over previous
//
#include <hip/hip_runtime.h>

#define BATCH  4096
#define TLEN   750
#define NK     6               // pair offsets k=1..6 (k=0 contributes exactly 0)
#define LPW    60              // lanes owning columns per wave
#define CPL    2               // columns per lane (float2)
#define OWN    (LPW*CPL)       // 120 owned columns per wave
#define NSTRIP 7               // 7*120 = 840 >= 750
#define WPB    4               // waves per block
#define NTH    256
#define NGR    64              // row-groups
#define RPB    (BATCH/NGR)     // 64 rows per block
#define RPW    (RPB/WPB)       // 16 rows per wave
#define QSZ    (2*NK*128)      // 1536 floats per (strip,group)
#define SLOTS  (NSTRIP*QSZ)    // 10752 = 42*256
#define K2GRID (SLOTS/256)     // 42 blocks
#define TP     752             // pitch of T rows (i-index)

// ---------------- helpers ----------------

template<int NW>
__device__ __forceinline__ float block_reduce(float v, float* red) {
    #pragma unroll
    for (int off = 32; off > 0; off >>= 1) v += __shfl_down(v, off, 64);
    const int t = threadIdx.x;
    if ((t & 63) == 0) red[t >> 6] = v;
    __syncthreads();
    float r = 0.f;
    if (t == 0) {
        #pragma unroll
        for (int w = 0; w < NW; ++w) r += red[w];
    }
    __syncthreads();
    return r;
}

__device__ __forceinline__ float2 shfl_down2(float2 v, int d) {
    float2 r;
    r.x = __shfl_down(v.x, d, 64);
    r.y = __shfl_down(v.y, d, 64);
    return r;
}

// ---------------- K1: strip x row-group pair partials ----------------
// Lane owns 2 columns (float2). Neighbors k=1..6 come from 3 float2 shuffles.
// Lanes 60..63 are halo; clamped/garbage slots are finite and never consumed.
__global__ __launch_bounds__(NTH) void actloss_k1(
        const float* __restrict__ a, const float* __restrict__ a2,
        float* __restrict__ p, float* __restrict__ resp,
        unsigned* __restrict__ ctr) {
    const int t = threadIdx.x;
    const int w = t >> 6;
    const int l = t & 63;
    const int s = (int)(blockIdx.x % NSTRIP);
    const int g = (int)(blockIdx.x / NSTRIP);
    if (blockIdx.x == 0 && t == 0) *ctr = 0u;   // K2 sees this via stream order

    const int colr = s * OWN + 2 * l;                       // even
    const int col  = colr <= TLEN - 2 ? colr : TLEN - 2;    // clamp, keep 8B align
    const bool own = (l < LPW) && (colr < TLEN);            // both cols valid together

    float s1[CPL][NK], s2[CPL][NK];
    #pragma unroll
    for (int c = 0; c < CPL; ++c)
        #pragma unroll
        for (int k = 0; k < NK; ++k) { s1[c][k] = 0.f; s2[c][k] = 0.f; }
    float res = 0.f;

    const int b0 = g * RPB + w * RPW;
    #pragma unroll 4
    for (int r = 0; r < RPW; ++r) {
        const size_t off = (size_t)(b0 + r) * TLEN + col;
        const float2 av = *reinterpret_cast<const float2*>(a + off);
        const float2 bv = *reinterpret_cast<const float2*>(a2 + off);
        const float2 a1 = shfl_down2(av, 1), a2v = shfl_down2(av, 2), a3v = shfl_down2(av, 3);
        const float2 b1 = shfl_down2(bv, 1), b2v = shfl_down2(bv, 2), b3v = shfl_down2(bv, 3);
        const float n[8] = {av.x, av.y, a1.x, a1.y, a2v.x, a2v.y, a3v.x, a3v.y};
        const float m[8] = {bv.x, bv.y, b1.x, b1.y, b2v.x, b2v.y, b3v.x, b3v.y};
        #pragma unroll
        for (int k = 1; k <= NK; ++k) {
            const float d0 = n[0] - n[k];
            s1[0][k - 1] = fmaf(d0, d0, s1[0][k - 1]);
            s2[0][k - 1] += fabsf(m[0] - m[k]);
            const float d1 = n[1] - n[1 + k];
            s1[1][k - 1] = fmaf(d1, d1, s1[1][k - 1]);
            s2[1][k - 1] += fabsf(m[1] - m[1 + k]);
        }
        if (own) {
            const float r0 = av.x - bv.x;
            const float r1 = av.y - bv.y;
            res = fmaf(r0, r0, res);
            res = fmaf(r1, r1, res);
        }
    }

    // cross-wave reduce in LDS -> one 1536-float partial per block
    __shared__ float lds[WPB][QSZ];
    __shared__ float rw[WPB];
    #pragma unroll
    for (int k = 0; k < NK; ++k) {
        lds[w][k * 128 + 2 * l]                 = s1[0][k];
        lds[w][k * 128 + 2 * l + 1]             = s1[1][k];
        lds[w][NK * 128 + k * 128 + 2 * l]      = s2[0][k];
        lds[w][NK * 128 + k * 128 + 2 * l + 1]  = s2[1][k];
    }
    #pragma unroll
    for (int off = 32; off > 0; off >>= 1) res += __shfl_down(res, off, 64);
    if (l == 0) rw[w] = res;
    __syncthreads();

    float* pg = p + (size_t)g * SLOTS + (size_t)s * QSZ;
    for (int q = t; q < QSZ; q += NTH)
        pg[q] = (lds[0][q] + lds[1][q]) + (lds[2][q] + lds[3][q]);
    if (t == 0) resp[blockIdx.x] = (rw[0] + rw[1]) + (rw[2] + rw[3]);
}

// ---------------- K2: final slot sums + last-block finish ----------------
__global__ __launch_bounds__(256) void actloss_k2(
        const float* __restrict__ p, const float* __restrict__ resp,
        float* __restrict__ fin, unsigned* __restrict__ ctr,
        float* __restrict__ out) {
    const int t = threadIdx.x;
    const int slot = (int)blockIdx.x * 256 + t;   // SLOTS = 42*256: always in range

    {
        float sum = 0.f;
        #pragma unroll 8
        for (int g = 0; g < NGR; ++g) sum += p[(size_t)g * SLOTS + slot];
        fin[slot] = sum;
    }

    __threadfence();
    __syncthreads();
    __shared__ unsigned last;
    if (t == 0) last = (atomicAdd(ctr, 1u) == (unsigned)(K2GRID - 1)) ? 1u : 0u;
    __syncthreads();
    if (!last) return;
    __threadfence();   // acquire: see all blocks' fin stores

    __shared__ float sm[SLOTS];      // ~43 KB
    __shared__ float Tl[NK * TP];    // ~18 KB
    for (int q = t; q < SLOTS; q += 256) sm[q] = fin[q];
    __syncthreads();

    // T[k][i] = exp(-0.5*S1)*S2 for valid pairs (i, i+k), i+k <= 749
    for (int e = t; e < NSTRIP * LPW * CPL * NK; e += 256) {   // 5040
        const int k = e % NK + 1;
        int u = e / NK;
        const int c = u % CPL; u /= CPL;
        const int l = u % LPW;
        const int s = u / LPW;
        const int i = s * OWN + 2 * l + c;
        if (i + k <= TLEN - 1) {
            const int sl = s * QSZ + (k - 1) * 128 + 2 * l + c;
            Tl[(k - 1) * TP + i] = expf(-0.5f * sm[sl]) * sm[sl + NK * 128];
        }
    }
    __syncthreads();

    // map the 8250 (i,j) window terms onto pairs
    float acc = 0.f;
    for (int idx = t; idx < TLEN * 11; idx += 256) {
        const int i = idx / 11, j = idx - i * 11;
        int c = i + j - 6;
        c = c < 0 ? 0 : (c > TLEN - 1 ? TLEN - 1 : c);
        const int k = i < c ? c - i : i - c;
        if (k > 0) acc += Tl[(k - 1) * TP + (i < c ? i : c)];
    }
    float racc = 0.f;
    for (int q = t; q < NGR * NSTRIP; q += 256) racc += resp[q];

    __shared__ float red[4];
    const float accR  = block_reduce<4>(acc, red);
    const float raccR = block_reduce<4>(racc, red);
    if (t == 0) out[0] = (accR + 0.1f * raccR) * (1.0f / (float)BATCH);
}

// ---------------- fallback slow path (round-1, known-good) ----------------

__global__ __launch_bounds__(256) void actloss_col_kernel(
        const float* __restrict__ a, const float* __restrict__ a2,
        float* __restrict__ part) {
    const int i = blockIdx.x;
    const int t = threadIdx.x;
    __shared__ float red[4];
    int cidx[11];
    #pragma unroll
    for (int j = 0; j < 11; ++j) {
        int c = i + j - 6;
        cidx[j] = c < 0 ? 0 : (c > TLEN - 1 ? TLEN - 1 : c);
    }
    float s1[11], s2[11];
    #pragma unroll
    for (int j = 0; j < 11; ++j) { s1[j] = 0.f; s2[j] = 0.f; }
    float resacc = 0.f;
    for (int b = t; b < BATCH; b += 256) {
        const float* arow  = a  + (size_t)b * TLEN;
        const float* a2row = a2 + (size_t)b * TLEN;
        const float ai = arow[i], a2i = a2row[i];
        const float r = ai - a2i;
        resacc = fmaf(r, r, resacc);
        #pragma unroll
        for (int j = 0; j < 11; ++j) {
            const float d = ai - arow[cidx[j]];
            s1[j] = fmaf(d, d, s1[j]);
            s2[j] += fabsf(a2i - a2row[cidx[j]]);
        }
    }
    float term = 0.f;
    #pragma unroll
    for (int j = 0; j < 11; ++j) {
        const float s1r = block_reduce<4>(s1[j], red);
        const float s2r = block_reduce<4>(s2[j], red);
        if (t == 0) term += expf(-0.5f * s1r) * s2r;
    }
    const float resr = block_reduce<4>(resacc, red);
    if (t == 0) part[i] = (term + 0.1f * resr) * (1.0f / (float)BATCH);
}

__global__ __launch_bounds__(256) void actloss_fallback_reduce(
        const float* __restrict__ part, float* __restrict__ out) {
    __shared__ float red[4];
    float v = 0.f;
    for (int k = threadIdx.x; k < TLEN; k += 256) v += part[k];
    const float r = block_reduce<4>(v, red);
    if (threadIdx.x == 0) out[0] = r;
}

// ---------------- launcher ----------------

extern "C" void kernel_launch(void* const* d_in, const int* in_sizes, int n_in,
                              void* d_out, int out_size, void* d_ws, size_t ws_size,
                              hipStream_t stream) {
    const float* a  = (const float*)d_in[0];   // actioness
    const float* a2 = (const float*)d_in[1];   // actioness_2
    float* out = (float*)d_out;
    float* ws  = (float*)d_ws;

    const size_t need = ((size_t)NGR * SLOTS + SLOTS + (size_t)NGR * NSTRIP + 16)
                        * sizeof(float);
    if (ws_size >= need) {
        float*    p    = ws;
        float*    fin  = p + (size_t)NGR * SLOTS;
        float*    resp = fin + SLOTS;
        unsigned* ctr  = (unsigned*)(resp + (size_t)NGR * NSTRIP);
        actloss_k1<<<NGR * NSTRIP, NTH, 0, stream>>>(a, a2, p, resp, ctr);
        actloss_k2<<<K2GRID, 256, 0, stream>>>(p, resp, fin, ctr, out);
    } else {
        float* part = ws;   // 750 floats
        actloss_col_kernel<<<TLEN, 256, 0, stream>>>(a, a2, part);
        actloss_fallback_reduce<<<1, 256, 0, stream>>>(part, out);
    }
}